// Round 6
// baseline (400.472 us; speedup 1.0000x reference)
//
#include <hip/hip_runtime.h>
#include <math.h>

#define NB 16
#define LL 512
#define CIN 32
#define DM 128
#define DS 16
#define DI 256
#define DTR 8
#define NCOL 3072
#define KTOT 65536
#define ROWS 8192
#define CH 32            // scan chunks
#define CLEN 16          // steps per chunk
#define KC 256           // k_final k-chunk
#define KS 256           // k_final splits
#define OUTSZ 49152

__device__ __forceinline__ float sigmoidf_(float x){ return 1.f/(1.f+expf(-x)); }
__device__ __forceinline__ float softplusf_(float x){ return (x > 20.f) ? x : log1pf(expf(x)); }

// Fused front-end: h = x@W_in+b_in ; xz = h@W_inproj ; u = silu(causal_conv4(u_half)+cb) ; z = z_half.
// Block = 8 output rows of one batch; computes 11 rows of u_pre in LDS for the conv overlap.
__global__ void __launch_bounds__(256) k_A(
    const float* __restrict__ x, const float* __restrict__ W_in,
    const float* __restrict__ b_in, const float* __restrict__ W_ip,
    const float* __restrict__ cw, const float* __restrict__ cb,
    float* __restrict__ u, float* __restrict__ z) {
  __shared__ float xs[11][32];
  __shared__ float hs[11][128];
  __shared__ float up[11][256];
  int t = threadIdx.x;
  int r0 = blockIdx.x * 8;            // global row (b*512 + l0)
  int b  = r0 >> 9;
  int l0 = r0 & 511;
  // stage x rows l0-3 .. l0+7 (zero for l<0)
  for (int i=t; i<11*32; i+=256) {
    int r = i >> 5, c2 = i & 31;
    int li = l0 - 3 + r;
    xs[r][c2] = (li >= 0) ? x[((b<<9)+li)*CIN + c2] : 0.f;
  }
  __syncthreads();
  // h = x@W_in + b_in (11 x 128)
  for (int i=t; i<11*128; i+=256) {
    int r = i >> 7, c2 = i & 127;
    float acc = b_in[c2];
    #pragma unroll
    for (int k=0;k<CIN;k++) acc = fmaf(xs[r][k], W_in[k*DM+c2], acc);
    hs[r][c2] = acc;
  }
  __syncthreads();
  // u_pre = h @ W_ip[:, 0:256] (11 x 256)
  for (int i=t; i<11*256; i+=256) {
    int r = i >> 8, c2 = i & 255;
    float acc = 0.f;
    #pragma unroll 8
    for (int k4=0;k4<DM/4;k4++) {
      float4 hv = *(const float4*)&hs[r][k4*4];
      acc = fmaf(hv.x, W_ip[(k4*4+0)*512 + c2], acc);
      acc = fmaf(hv.y, W_ip[(k4*4+1)*512 + c2], acc);
      acc = fmaf(hv.z, W_ip[(k4*4+2)*512 + c2], acc);
      acc = fmaf(hv.w, W_ip[(k4*4+3)*512 + c2], acc);
    }
    up[r][c2] = acc;
  }
  __syncthreads();
  // per (row rr, d=t): z = h@W_ip[:,256+d]; u = silu(conv(up)+cb)
  for (int rr=0; rr<8; ++rr) {
    int gr = r0 + rr;
    float zacc = 0.f;
    #pragma unroll 8
    for (int k4=0;k4<DM/4;k4++) {
      float4 hv = *(const float4*)&hs[rr+3][k4*4];
      zacc = fmaf(hv.x, W_ip[(k4*4+0)*512 + 256 + t], zacc);
      zacc = fmaf(hv.y, W_ip[(k4*4+1)*512 + 256 + t], zacc);
      zacc = fmaf(hv.z, W_ip[(k4*4+2)*512 + 256 + t], zacc);
      zacc = fmaf(hv.w, W_ip[(k4*4+3)*512 + 256 + t], zacc);
    }
    float s = cb[t];
    #pragma unroll
    for (int j=0;j<4;j++) {
      int li = l0 + rr - 3 + j;
      if (li >= 0) s = fmaf(cw[t*4+j], up[rr+j][t], s);
    }
    u[gr*DI + t] = s * sigmoidf_(s);
    z[gr*DI + t] = zacc;
  }
}

// scan pass 1: block=(b,chunk), thread=d. xproj (dt-rank+B cols) + dt computed inline from LDS u.
__global__ void __launch_bounds__(256) k_scan1(
    const float* __restrict__ u, const float* __restrict__ W_xp,
    const float* __restrict__ Wdt, const float* __restrict__ bdt,
    const float* __restrict__ A_log,
    float* __restrict__ Hc, float* __restrict__ Sdt) {
  __shared__ float us[CLEN][256];
  __shared__ float xl[CLEN][24];
  int t = threadIdx.x;
  int b = blockIdx.x >> 5, c = blockIdx.x & 31, d = t;
  int l0 = c * CLEN;
  for (int i=t; i<CLEN*64; i+=256) {
    int r = i >> 6, q = i & 63;
    *(float4*)&us[r][q*4] = *(const float4*)&u[(((b<<9)+l0+r)<<8) + q*4];
  }
  __syncthreads();
  for (int i=t; i<CLEN*24; i+=256) {
    int r = i / 24, cc = i - r*24;
    float acc = 0.f;
    #pragma unroll 8
    for (int k4=0;k4<64;k4++) {
      float4 uv = *(const float4*)&us[r][k4*4];
      acc = fmaf(uv.x, W_xp[(k4*4+0)*40+cc], acc);
      acc = fmaf(uv.y, W_xp[(k4*4+1)*40+cc], acc);
      acc = fmaf(uv.z, W_xp[(k4*4+2)*40+cc], acc);
      acc = fmaf(uv.w, W_xp[(k4*4+3)*40+cc], acc);
    }
    xl[r][cc] = acc;
  }
  __syncthreads();
  float A[16], hsv[16];
  #pragma unroll
  for (int n=0;n<16;n++){ A[n] = -expf(A_log[d*16+n]); hsv[n]=0.f; }
  float wdt[DTR];
  #pragma unroll
  for (int j=0;j<DTR;j++) wdt[j] = Wdt[j*DI+d];
  float bdtv = bdt[d];
  float sdt = 0.f;
  for (int l=0;l<CLEN;++l) {
    float acc = bdtv;
    #pragma unroll
    for (int j=0;j<DTR;j++) acc = fmaf(xl[l][j], wdt[j], acc);
    float dtv = softplusf_(acc);
    sdt += dtv;
    float du = dtv * us[l][d];
    #pragma unroll
    for (int n=0;n<16;n++) {
      float a = expf(dtv*A[n]);
      hsv[n] = fmaf(a, hsv[n], du * xl[l][DTR+n]);
    }
  }
  int bd = (b<<8) + d;
  int base = (bd*CH + c)*16;
  #pragma unroll
  for (int n=0;n<16;n++) Hc[base+n] = hsv[n];
  Sdt[bd*CH + c] = sdt;
}

// pass 2: one thread per (b,d,n) chain; combine CH chunks; store chunk start states
__global__ void k_scan2(const float* __restrict__ A_log, const float* __restrict__ Hc,
                        const float* __restrict__ Sdt, float* __restrict__ Hst) {
  int idx = blockIdx.x*256 + threadIdx.x;   // 65536
  int n  = idx & 15;
  int bd = idx >> 4;
  int d  = bd & 255;
  float A = -expf(A_log[d*16+n]);
  float hs = 0.f;
  int base = bd*CH*16;
  #pragma unroll
  for (int c=0;c<CH;c++) {
    Hst[base + c*16 + n] = hs;
    float sdt = Sdt[bd*CH + c];
    hs = fmaf(expf(A*sdt), hs, Hc[base + c*16 + n]);
  }
}

// pass 3: replay chunk from start state; y=(scan+u*D)*silu(z) into LDS; fused mo = ym@W_out.
__global__ void __launch_bounds__(256) k_scan3(
    const float* __restrict__ u, const float* __restrict__ z,
    const float* __restrict__ W_xp, const float* __restrict__ Wdt,
    const float* __restrict__ bdt, const float* __restrict__ A_log,
    const float* __restrict__ Dp, const float* __restrict__ Hst,
    const float* __restrict__ W_out, float* __restrict__ mo) {
  __shared__ float us[CLEN][256];
  __shared__ float ym[CLEN][256];
  __shared__ float xl[CLEN][40];
  int t = threadIdx.x;
  int b = blockIdx.x >> 5, c = blockIdx.x & 31, d = t;
  int l0 = c * CLEN;
  for (int i=t; i<CLEN*64; i+=256) {
    int r = i >> 6, q = i & 63;
    *(float4*)&us[r][q*4] = *(const float4*)&u[(((b<<9)+l0+r)<<8) + q*4];
  }
  __syncthreads();
  for (int i=t; i<CLEN*40; i+=256) {
    int r = i / 40, cc = i - r*40;
    float acc = 0.f;
    #pragma unroll 8
    for (int k4=0;k4<64;k4++) {
      float4 uv = *(const float4*)&us[r][k4*4];
      acc = fmaf(uv.x, W_xp[(k4*4+0)*40+cc], acc);
      acc = fmaf(uv.y, W_xp[(k4*4+1)*40+cc], acc);
      acc = fmaf(uv.z, W_xp[(k4*4+2)*40+cc], acc);
      acc = fmaf(uv.w, W_xp[(k4*4+3)*40+cc], acc);
    }
    xl[r][cc] = acc;
  }
  __syncthreads();
  int bd = (b<<8) + d;
  int base = (bd*CH + c)*16;
  float A[16], hsv[16];
  #pragma unroll
  for (int n=0;n<16;n++){ A[n] = -expf(A_log[d*16+n]); hsv[n] = Hst[base+n]; }
  float wdt[DTR];
  #pragma unroll
  for (int j=0;j<DTR;j++) wdt[j] = Wdt[j*DI+d];
  float bdtv = bdt[d];
  float Dv = Dp[d];
  for (int l=0;l<CLEN;++l) {
    int row = (b<<9) + l0 + l;
    float acc = bdtv;
    #pragma unroll
    for (int j=0;j<DTR;j++) acc = fmaf(xl[l][j], wdt[j], acc);
    float dtv = softplusf_(acc);
    float uv = us[l][d];
    float zv = z[(row<<8) + d];
    float du = dtv * uv;
    float y = 0.f;
    #pragma unroll
    for (int n=0;n<16;n++) {
      float a = expf(dtv*A[n]);
      hsv[n] = fmaf(a, hsv[n], du * xl[l][DTR+n]);
      y = fmaf(hsv[n], xl[l][DTR+DS+n], y);
    }
    y = fmaf(uv, Dv, y);
    ym[l][d] = y * (zv * sigmoidf_(zv));
  }
  __syncthreads();
  // mo = ym @ W_out for the 16 rows: thread = (col cc, 8-row group)
  int cc = t & 127;
  int rg = (t >> 7) * 8;
  float acc[8] = {};
  for (int k4=0;k4<64;k4++) {
    float w0 = W_out[(k4*4+0)*DM+cc];
    float w1 = W_out[(k4*4+1)*DM+cc];
    float w2 = W_out[(k4*4+2)*DM+cc];
    float w3 = W_out[(k4*4+3)*DM+cc];
    #pragma unroll
    for (int o=0;o<8;o++) {
      float4 yv = *(const float4*)&ym[rg+o][k4*4];
      acc[o] = fmaf(yv.w, w3, fmaf(yv.z, w2, fmaf(yv.y, w1, fmaf(yv.x, w0, acc[o]))));
    }
  }
  #pragma unroll
  for (int o=0;o<8;o++) mo[((b<<9)+l0+rg+o)*DM + cc] = acc[o];
}

// final: part[s] = flat(16 x 65536) @ W_outproj slab, full-row blocks.
// 1024 threads; thread owns cols {t, t+1024, t+2048} x 16 rows. Block streams
// 256 contiguous 12KB W rows (3MB contiguous). Grid = KS = 256 = 1 block/CU.
__global__ void __launch_bounds__(1024) k_final(
    const float* __restrict__ flat, const float* __restrict__ W,
    float* __restrict__ part) {
  __shared__ float lds[KC][16];            // [kk][b], 16 KB
  int t = threadIdx.x;
  int k0 = blockIdx.x * KC;
  {
    int bb = t & 15, kk4 = t >> 4;         // 16 x 64 float4
    float4 v = *(const float4*)(flat + bb*KTOT + k0 + kk4*4);
    lds[kk4*4+0][bb]=v.x; lds[kk4*4+1][bb]=v.y;
    lds[kk4*4+2][bb]=v.z; lds[kk4*4+3][bb]=v.w;
  }
  __syncthreads();
  float acc[16][3];
  #pragma unroll
  for (int bq=0;bq<16;bq++){acc[bq][0]=0.f;acc[bq][1]=0.f;acc[bq][2]=0.f;}
  const float* Wp = W + (size_t)k0*NCOL + t;
  for (int kk=0; kk<KC; kk+=2) {
    size_t o0 = (size_t)kk*NCOL;
    float w00=Wp[o0],      w01=Wp[o0+1024], w02=Wp[o0+2048];
    float w10=Wp[o0+3072], w11=Wp[o0+4096], w12=Wp[o0+5120];
    const float4* L0 = (const float4*)&lds[kk][0];
    const float4* L1 = (const float4*)&lds[kk+1][0];
    float4 a0=L0[0],a1=L0[1],a2=L0[2],a3=L0[3];
    float4 b0=L1[0],b1=L1[1],b2=L1[2],b3=L1[3];
    float fa[16]={a0.x,a0.y,a0.z,a0.w,a1.x,a1.y,a1.z,a1.w,
                  a2.x,a2.y,a2.z,a2.w,a3.x,a3.y,a3.z,a3.w};
    float fb[16]={b0.x,b0.y,b0.z,b0.w,b1.x,b1.y,b1.z,b1.w,
                  b2.x,b2.y,b2.z,b2.w,b3.x,b3.y,b3.z,b3.w};
    #pragma unroll
    for (int bq=0;bq<16;bq++){
      acc[bq][0]=fmaf(fa[bq],w00,acc[bq][0]); acc[bq][0]=fmaf(fb[bq],w10,acc[bq][0]);
      acc[bq][1]=fmaf(fa[bq],w01,acc[bq][1]); acc[bq][1]=fmaf(fb[bq],w11,acc[bq][1]);
      acc[bq][2]=fmaf(fa[bq],w02,acc[bq][2]); acc[bq][2]=fmaf(fb[bq],w12,acc[bq][2]);
    }
  }
  float* p = part + (size_t)blockIdx.x*OUTSZ;
  #pragma unroll
  for (int bq=0;bq<16;bq++){
    p[bq*NCOL + t]        = acc[bq][0];
    p[bq*NCOL + 1024 + t] = acc[bq][1];
    p[bq*NCOL + 2048 + t] = acc[bq][2];
  }
}

// out = sum_s part[s] + bias
__global__ void k_reduce(const float* __restrict__ part, const float* __restrict__ bias,
                         float* __restrict__ out) {
  int idx = blockIdx.x*256 + threadIdx.x; // OUTSZ
  float acc = bias[idx % NCOL];
  #pragma unroll 8
  for (int s=0;s<KS;s++) acc += part[(size_t)s*OUTSZ + idx];
  out[idx] = acc;
}

extern "C" void kernel_launch(void* const* d_in, const int* in_sizes, int n_in,
                              void* d_out, int out_size, void* d_ws, size_t ws_size,
                              hipStream_t stream) {
  const float* x        = (const float*)d_in[0];
  const float* W_in     = (const float*)d_in[1];
  const float* b_in     = (const float*)d_in[2];
  const float* W_inproj = (const float*)d_in[3];
  const float* conv_w   = (const float*)d_in[4];
  const float* conv_b   = (const float*)d_in[5];
  const float* W_xproj  = (const float*)d_in[6];
  const float* W_dt     = (const float*)d_in[7];
  const float* b_dt     = (const float*)d_in[8];
  const float* A_log    = (const float*)d_in[9];
  const float* Dp       = (const float*)d_in[10];
  const float* W_out    = (const float*)d_in[11];
  const float* W_outproj= (const float*)d_in[12];
  const float* b_outproj= (const float*)d_in[13];
  float* out = (float*)d_out;
  float* ws  = (float*)d_ws;

  float* u    = ws;            // 2097152
  float* z    = ws + 2097152;  // 2097152
  float* Hc   = ws + 4194304;  // 2097152
  float* Sdt  = ws + 6291456;  // 131072
  float* Hst  = ws + 6422528;  // 2097152
  float* mo   = ws + 8519680;  // 1048576
  float* part = ws + 9568256;  // 12582912 -> total ~88.6 MB

  k_A     <<<1024, 256, 0, stream>>>(x, W_in, b_in, W_inproj, conv_w, conv_b, u, z);
  k_scan1 <<<512,  256, 0, stream>>>(u, W_xproj, W_dt, b_dt, A_log, Hc, Sdt);
  k_scan2 <<<256,  256, 0, stream>>>(A_log, Hc, Sdt, Hst);
  k_scan3 <<<512,  256, 0, stream>>>(u, z, W_xproj, W_dt, b_dt, A_log, Dp, Hst, W_out, mo);
  k_final <<<KS,  1024, 0, stream>>>(mo, W_outproj, part);
  k_reduce<<<192,  256, 0, stream>>>(part, b_outproj, out);
}

// Round 8
// 338.778 us; speedup vs baseline: 1.1821x; 1.1821x over previous
//
#include <hip/hip_runtime.h>
#include <math.h>

#define NB 16
#define LL 512
#define CIN 32
#define DM 128
#define DS 16
#define DI 256
#define DTR 8
#define NCOL 3072
#define KTOT 65536
#define ROWS 8192
#define CH 32            // scan chunks
#define CLEN 16          // steps per chunk
#define KC 512           // k_final k-chunk
#define KS 128           // k_final splits
#define OUTSZ 49152

typedef float f32x2 __attribute__((ext_vector_type(2)));

__device__ __forceinline__ float sigmoidf_(float x){ return 1.f/(1.f+expf(-x)); }
__device__ __forceinline__ float softplusf_(float x){ return (x > 20.f) ? x : log1pf(expf(x)); }

// h = x @ W_in + b_in   (ROWS x 128, K=32)
__global__ void k_in(const float* __restrict__ x, const float* __restrict__ W,
                     const float* __restrict__ bias, float* __restrict__ h) {
  int idx = blockIdx.x*256 + threadIdx.x;
  int r = idx >> 7, c = idx & 127;
  const float* xr = x + r*CIN;
  float acc = bias[c];
  #pragma unroll
  for (int k=0;k<CIN;k++) acc = fmaf(xr[k], W[k*DM+c], acc);
  h[idx] = acc;
}

// xz = h @ W_inproj -> u_pre (cols 0..255), z (cols 256..511). K=128.
__global__ void k_inproj(const float* __restrict__ h, const float* __restrict__ W,
                         float* __restrict__ u_pre, float* __restrict__ z) {
  int t = threadIdx.x;
  int c0 = (t & 127)*4;
  int r0 = blockIdx.x*8 + (t>>7)*4;
  float acc[4][4] = {};
  for (int k=0;k<DM;k++) {
    float4 w = *(const float4*)(W + k*512 + c0);
    #pragma unroll
    for (int i=0;i<4;i++) {
      float hv = h[(r0+i)*DM + k];
      acc[i][0]=fmaf(hv,w.x,acc[i][0]); acc[i][1]=fmaf(hv,w.y,acc[i][1]);
      acc[i][2]=fmaf(hv,w.z,acc[i][2]); acc[i][3]=fmaf(hv,w.w,acc[i][3]);
    }
  }
  #pragma unroll
  for (int i=0;i<4;i++) {
    float4 v = make_float4(acc[i][0],acc[i][1],acc[i][2],acc[i][3]);
    if (c0 < 256) *(float4*)(u_pre + (r0+i)*DI + c0) = v;
    else          *(float4*)(z     + (r0+i)*DI + (c0-256)) = v;
  }
}

// causal depthwise conv (k=4) + bias + silu
__global__ void k_conv(const float* __restrict__ u_pre, const float* __restrict__ cw,
                       const float* __restrict__ cb, float* __restrict__ u) {
  int idx = blockIdx.x*256 + threadIdx.x; // NB*LL*DI
  int d = idx & 255;
  int l = (idx >> 8) & 511;
  int b = idx >> 17;
  float s = cb[d];
  #pragma unroll
  for (int j=0;j<4;j++) {
    int li = l - 3 + j;
    if (li >= 0) s = fmaf(cw[d*4+j], u_pre[(((b<<9)+li)<<8) + d], s);
  }
  u[idx] = s * sigmoidf_(s);
}

// xdbc = u @ W_xproj  (ROWS x 40, K=256)
__global__ void k_xproj(const float* __restrict__ u, const float* __restrict__ W,
                        float* __restrict__ xdbc) {
  int idx = blockIdx.x*256 + threadIdx.x; // ROWS*40
  int r = idx / 40, c = idx - r*40;
  const float4* ur4 = (const float4*)(u + r*DI);
  float acc = 0.f;
  #pragma unroll 8
  for (int k4=0;k4<DI/4;k4++) {
    float4 uv = ur4[k4];
    acc = fmaf(uv.x, W[(k4*4+0)*40+c], acc);
    acc = fmaf(uv.y, W[(k4*4+1)*40+c], acc);
    acc = fmaf(uv.z, W[(k4*4+2)*40+c], acc);
    acc = fmaf(uv.w, W[(k4*4+3)*40+c], acc);
  }
  xdbc[idx] = acc;
}

// scan pass 1: per (b,chunk) block, thread=d. dt recomputed inline.
__global__ void k_scan1(const float* __restrict__ u, const float* __restrict__ xdbc,
                        const float* __restrict__ Wdt, const float* __restrict__ bdt,
                        const float* __restrict__ A_log,
                        float* __restrict__ Hc, float* __restrict__ Sdt) {
  int b = blockIdx.x >> 5, c = blockIdx.x & 31, d = threadIdx.x;
  float A[16]; float hs[16];
  #pragma unroll
  for (int n=0;n<16;n++) { A[n] = -expf(A_log[d*16+n]); hs[n]=0.f; }
  float wdt[DTR];
  #pragma unroll
  for (int j=0;j<DTR;j++) wdt[j] = Wdt[j*DI+d];
  float bdtv = bdt[d];
  float sdt = 0.f;
  int l0 = c*CLEN;
  for (int l=l0; l<l0+CLEN; ++l) {
    int row = (b<<9) + l;
    const float* xr = xdbc + row*40;
    float acc = bdtv;
    #pragma unroll
    for (int j=0;j<DTR;j++) acc = fmaf(xr[j], wdt[j], acc);
    float dtv = softplusf_(acc);
    float uv  = u[(row<<8) + d];
    sdt += dtv;
    float du = dtv*uv;
    const float* Bp = xr + DTR;
    #pragma unroll
    for (int n=0;n<16;n++) {
      float a = expf(dtv*A[n]);
      hs[n] = fmaf(a, hs[n], du*Bp[n]);
    }
  }
  int bd = (b<<8) + d;
  int base = (bd*CH + c)*16;
  #pragma unroll
  for (int n=0;n<16;n++) Hc[base+n] = hs[n];
  Sdt[bd*CH + c] = sdt;
}

// pass 2: one thread per (b,d,n) chain; combine CH chunks; store chunk start states
__global__ void k_scan2(const float* __restrict__ A_log, const float* __restrict__ Hc,
                        const float* __restrict__ Sdt, float* __restrict__ Hst) {
  int idx = blockIdx.x*256 + threadIdx.x;   // NB*DI*DS = 65536
  int n  = idx & 15;
  int bd = idx >> 4;
  int d  = bd & 255;
  float A = -expf(A_log[d*16+n]);
  float hs = 0.f;
  int base = bd*CH*16;
  #pragma unroll
  for (int c=0;c<CH;c++) {
    Hst[base + c*16 + n] = hs;
    float sdt = Sdt[bd*CH + c];
    hs = fmaf(expf(A*sdt), hs, Hc[base + c*16 + n]);
  }
}

// pass 3: replay each chunk from correct start state; fuse y = (scan + u*D)*silu(z)
__global__ void k_scan3(const float* __restrict__ u, const float* __restrict__ z,
                        const float* __restrict__ xdbc,
                        const float* __restrict__ Wdt, const float* __restrict__ bdt,
                        const float* __restrict__ A_log, const float* __restrict__ Dp,
                        const float* __restrict__ Hst, float* __restrict__ ym) {
  int b = blockIdx.x >> 5, c = blockIdx.x & 31, d = threadIdx.x;
  int bd = (b<<8) + d;
  int base = (bd*CH + c)*16;
  float A[16]; float hs[16];
  #pragma unroll
  for (int n=0;n<16;n++) { A[n] = -expf(A_log[d*16+n]); hs[n] = Hst[base+n]; }
  float wdt[DTR];
  #pragma unroll
  for (int j=0;j<DTR;j++) wdt[j] = Wdt[j*DI+d];
  float bdtv = bdt[d];
  float Dv = Dp[d];
  int l0 = c*CLEN;
  for (int l=l0; l<l0+CLEN; ++l) {
    int row = (b<<9) + l;
    const float* xr = xdbc + row*40;
    float acc = bdtv;
    #pragma unroll
    for (int j=0;j<DTR;j++) acc = fmaf(xr[j], wdt[j], acc);
    float dtv = softplusf_(acc);
    float uv  = u[(row<<8) + d];
    float zv  = z[(row<<8) + d];
    float du = dtv*uv;
    const float* Bp = xr + DTR;
    const float* Cp = xr + DTR + DS;
    float y = 0.f;
    #pragma unroll
    for (int n=0;n<16;n++) {
      float a = expf(dtv*A[n]);
      hs[n] = fmaf(a, hs[n], du*Bp[n]);
      y = fmaf(hs[n], Cp[n], y);
    }
    y = fmaf(uv, Dv, y);
    ym[(row<<8)+d] = y * (zv * sigmoidf_(zv));
  }
}

// m_out = ym @ W_out (ROWS x 128, K=256). 1024 blocks, 4 rows x 1 col per thread.
__global__ void k_out(const float* __restrict__ ym, const float* __restrict__ W,
                      float* __restrict__ mo) {
  int t = threadIdx.x;
  int c  = t & 127;
  int r0 = blockIdx.x*8 + (t>>7)*4;
  float acc[4] = {0.f,0.f,0.f,0.f};
  #pragma unroll 4
  for (int k=0;k<DI;k++) {
    float w = W[k*DM + c];
    #pragma unroll
    for (int i=0;i<4;i++) acc[i] = fmaf(ym[(r0+i)*DI + k], w, acc[i]);
  }
  #pragma unroll
  for (int i=0;i<4;i++) mo[(r0+i)*DM + c] = acc[i];
}

// final: pred partials = flat(16 x 65536) @ W_outproj(65536 x 3072), split-K.
// Each thread: 2 cols x all 16 rows. 6 n-tiles x 128 splits = 768 blocks (3/CU).
// W stream via nontemporal loads; k unrolled x4 (4 independent loads in flight).
__global__ void __launch_bounds__(256) k_final(
    const float* __restrict__ flat, const float* __restrict__ W,
    float* __restrict__ part) {
  __shared__ float lds[KC][16];            // transposed: [kk][b], 32 KB
  int t = threadIdx.x;
  int n0 = blockIdx.x * 512;               // 6 n-tiles of 512 cols
  int k0 = blockIdx.y * KC;                // KS k-splits of KC
  // stage flat chunk (16 rows x KC k) transposed into LDS
  for (int i = t; i < 16*(KC/4); i += 256) {
    int bb  = i & 15;
    int kk4 = i >> 4;
    float4 v = *(const float4*)(flat + bb*KTOT + k0 + kk4*4);
    lds[kk4*4+0][bb] = v.x; lds[kk4*4+1][bb] = v.y;
    lds[kk4*4+2][bb] = v.z; lds[kk4*4+3][bb] = v.w;
  }
  __syncthreads();
  int c0 = n0 + t*2;
  float2 acc[16];
  #pragma unroll
  for (int b=0;b<16;b++) acc[b] = make_float2(0.f,0.f);
  const float* Wp = W + (size_t)k0*NCOL + c0;
  for (int kk=0; kk<KC; kk+=4) {
    f32x2 w0 = __builtin_nontemporal_load((const f32x2*)(Wp + (size_t)(kk+0)*NCOL));
    f32x2 w1 = __builtin_nontemporal_load((const f32x2*)(Wp + (size_t)(kk+1)*NCOL));
    f32x2 w2 = __builtin_nontemporal_load((const f32x2*)(Wp + (size_t)(kk+2)*NCOL));
    f32x2 w3 = __builtin_nontemporal_load((const f32x2*)(Wp + (size_t)(kk+3)*NCOL));
    const float4* f0 = (const float4*)&lds[kk+0][0];
    const float4* f1 = (const float4*)&lds[kk+1][0];
    const float4* f2 = (const float4*)&lds[kk+2][0];
    const float4* f3 = (const float4*)&lds[kk+3][0];
    #pragma unroll
    for (int q=0;q<4;q++) {
      float4 fa = f0[q], fb = f1[q], fc = f2[q], fd = f3[q];
      float fs0[4] = {fa.x,fa.y,fa.z,fa.w};
      float fs1[4] = {fb.x,fb.y,fb.z,fb.w};
      float fs2[4] = {fc.x,fc.y,fc.z,fc.w};
      float fs3[4] = {fd.x,fd.y,fd.z,fd.w};
      #pragma unroll
      for (int j=0;j<4;j++) {
        int b = q*4+j;
        acc[b].x=fmaf(fs0[j],w0.x,acc[b].x); acc[b].y=fmaf(fs0[j],w0.y,acc[b].y);
        acc[b].x=fmaf(fs1[j],w1.x,acc[b].x); acc[b].y=fmaf(fs1[j],w1.y,acc[b].y);
        acc[b].x=fmaf(fs2[j],w2.x,acc[b].x); acc[b].y=fmaf(fs2[j],w2.y,acc[b].y);
        acc[b].x=fmaf(fs3[j],w3.x,acc[b].x); acc[b].y=fmaf(fs3[j],w3.y,acc[b].y);
      }
    }
  }
  float* p = part + (size_t)blockIdx.y*OUTSZ;
  #pragma unroll
  for (int b=0;b<16;b++) {
    f32x2 v; v.x = acc[b].x; v.y = acc[b].y;
    __builtin_nontemporal_store(v, (f32x2*)(p + b*NCOL + c0));
  }
}

// out = sum_s part[s] + bias
__global__ void k_reduce(const float* __restrict__ part, const float* __restrict__ bias,
                         float* __restrict__ out) {
  int idx = blockIdx.x*256 + threadIdx.x; // OUTSZ
  float acc = bias[idx % NCOL];
  #pragma unroll 8
  for (int s=0;s<KS;s++)
    acc += __builtin_nontemporal_load(part + (size_t)s*OUTSZ + idx);
  out[idx] = acc;
}

extern "C" void kernel_launch(void* const* d_in, const int* in_sizes, int n_in,
                              void* d_out, int out_size, void* d_ws, size_t ws_size,
                              hipStream_t stream) {
  const float* x        = (const float*)d_in[0];
  const float* W_in     = (const float*)d_in[1];
  const float* b_in     = (const float*)d_in[2];
  const float* W_inproj = (const float*)d_in[3];
  const float* conv_w   = (const float*)d_in[4];
  const float* conv_b   = (const float*)d_in[5];
  const float* W_xproj  = (const float*)d_in[6];
  const float* W_dt     = (const float*)d_in[7];
  const float* b_dt     = (const float*)d_in[8];
  const float* A_log    = (const float*)d_in[9];
  const float* Dp       = (const float*)d_in[10];
  const float* W_out    = (const float*)d_in[11];
  const float* W_outproj= (const float*)d_in[12];
  const float* b_outproj= (const float*)d_in[13];
  float* out = (float*)d_out;
  float* ws  = (float*)d_ws;

  float* h     = ws;            // 1048576
  float* u_pre = ws + 1048576;  // 2097152
  float* z     = ws + 3145728;  // 2097152
  float* u     = ws + 5242880;  // 2097152
  float* xdbc  = ws + 7340032;  // 327680
  float* Hc    = ws + 7667712;  // 2097152 (NB*DI*CH*16)
  float* Sdt   = ws + 9764864;  // 131072
  float* Hst   = ws + 9895936;  // 2097152
  float* ym    = ws + 11993088; // 2097152
  float* mo    = ws + 14090240; // 1048576
  float* part  = ws + 15138816; // 6291456 (KS*OUTSZ) -> total ~86 MB

  k_in     <<<4096, 256, 0, stream>>>(x, W_in, b_in, h);
  k_inproj <<<1024, 256, 0, stream>>>(h, W_inproj, u_pre, z);
  k_conv   <<<8192, 256, 0, stream>>>(u_pre, conv_w, conv_b, u);
  k_xproj  <<<1280, 256, 0, stream>>>(u, W_xproj, xdbc);
  k_scan1  <<<512,  256, 0, stream>>>(u, xdbc, W_dt, b_dt, A_log, Hc, Sdt);
  k_scan2  <<<256,  256, 0, stream>>>(A_log, Hc, Sdt, Hst);
  k_scan3  <<<512,  256, 0, stream>>>(u, z, xdbc, W_dt, b_dt, A_log, Dp, Hst, ym);
  k_out    <<<1024, 256, 0, stream>>>(ym, W_out, mo);
  k_final  <<<dim3(6, KS), 256, 0, stream>>>(mo, W_outproj, part);
  k_reduce <<<192,  256, 0, stream>>>(part, b_outproj, out);
}

// Round 9
// 338.703 us; speedup vs baseline: 1.1824x; 1.0002x over previous
//
#include <hip/hip_runtime.h>
#include <math.h>

#define NB 16
#define LL 512
#define CIN 32
#define DM 128
#define DS 16
#define DI 256
#define DTR 8
#define NCOL 3072
#define KTOT 65536
#define ROWS 8192
#define CH 32            // scan chunks
#define CLEN 16          // steps per chunk
#define KC 512           // k_final k-chunk
#define KS 128           // k_final splits
#define OUTSZ 49152

typedef float f32x2 __attribute__((ext_vector_type(2)));

__device__ __forceinline__ float sigmoidf_(float x){ return 1.f/(1.f+expf(-x)); }
__device__ __forceinline__ float softplusf_(float x){ return (x > 20.f) ? x : log1pf(expf(x)); }

// Fused front-end: h = x@W_in+b_in ; xz = h@W_inproj ; u = silu(causal_conv4(u_half)+cb) ; z = z_half.
// Block = 8 output rows of one batch; computes 11 rows of u_pre in LDS for the conv overlap.
__global__ void __launch_bounds__(256) k_A(
    const float* __restrict__ x, const float* __restrict__ W_in,
    const float* __restrict__ b_in, const float* __restrict__ W_ip,
    const float* __restrict__ cw, const float* __restrict__ cb,
    float* __restrict__ u, float* __restrict__ z) {
  __shared__ float xs[11][32];
  __shared__ float hs[11][128];
  __shared__ float up[11][256];
  int t = threadIdx.x;
  int r0 = blockIdx.x * 8;            // global row (b*512 + l0)
  int b  = r0 >> 9;
  int l0 = r0 & 511;
  for (int i=t; i<11*32; i+=256) {
    int r = i >> 5, c2 = i & 31;
    int li = l0 - 3 + r;
    xs[r][c2] = (li >= 0) ? x[((b<<9)+li)*CIN + c2] : 0.f;
  }
  __syncthreads();
  for (int i=t; i<11*128; i+=256) {
    int r = i >> 7, c2 = i & 127;
    float acc = b_in[c2];
    #pragma unroll
    for (int k=0;k<CIN;k++) acc = fmaf(xs[r][k], W_in[k*DM+c2], acc);
    hs[r][c2] = acc;
  }
  __syncthreads();
  for (int i=t; i<11*256; i+=256) {
    int r = i >> 8, c2 = i & 255;
    float acc = 0.f;
    #pragma unroll 8
    for (int k4=0;k4<DM/4;k4++) {
      float4 hv = *(const float4*)&hs[r][k4*4];
      acc = fmaf(hv.x, W_ip[(k4*4+0)*512 + c2], acc);
      acc = fmaf(hv.y, W_ip[(k4*4+1)*512 + c2], acc);
      acc = fmaf(hv.z, W_ip[(k4*4+2)*512 + c2], acc);
      acc = fmaf(hv.w, W_ip[(k4*4+3)*512 + c2], acc);
    }
    up[r][c2] = acc;
  }
  __syncthreads();
  for (int rr=0; rr<8; ++rr) {
    int gr = r0 + rr;
    float zacc = 0.f;
    #pragma unroll 8
    for (int k4=0;k4<DM/4;k4++) {
      float4 hv = *(const float4*)&hs[rr+3][k4*4];
      zacc = fmaf(hv.x, W_ip[(k4*4+0)*512 + 256 + t], zacc);
      zacc = fmaf(hv.y, W_ip[(k4*4+1)*512 + 256 + t], zacc);
      zacc = fmaf(hv.z, W_ip[(k4*4+2)*512 + 256 + t], zacc);
      zacc = fmaf(hv.w, W_ip[(k4*4+3)*512 + 256 + t], zacc);
    }
    float s = cb[t];
    #pragma unroll
    for (int j=0;j<4;j++) {
      int li = l0 + rr - 3 + j;
      if (li >= 0) s = fmaf(cw[t*4+j], up[rr+j][t], s);
    }
    u[gr*DI + t] = s * sigmoidf_(s);
    z[gr*DI + t] = zacc;
  }
}

// scan pass 1: block=(b,chunk), thread=d. xproj (dt+B cols) computed inline from LDS u.
__global__ void __launch_bounds__(256) k_scan1(
    const float* __restrict__ u, const float* __restrict__ W_xp,
    const float* __restrict__ Wdt, const float* __restrict__ bdt,
    const float* __restrict__ A_log,
    float* __restrict__ Hc, float* __restrict__ Sdt) {
  __shared__ float us[CLEN][256];
  __shared__ float xl[CLEN][24];
  int t = threadIdx.x;
  int b = blockIdx.x >> 5, c = blockIdx.x & 31, d = t;
  int l0 = c * CLEN;
  for (int i=t; i<CLEN*64; i+=256) {
    int r = i >> 6, q = i & 63;
    *(float4*)&us[r][q*4] = *(const float4*)&u[(((b<<9)+l0+r)<<8) + q*4];
  }
  __syncthreads();
  for (int i=t; i<CLEN*24; i+=256) {
    int r = i / 24, cc = i - r*24;
    float acc = 0.f;
    #pragma unroll 8
    for (int k4=0;k4<64;k4++) {
      float4 uv = *(const float4*)&us[r][k4*4];
      acc = fmaf(uv.x, W_xp[(k4*4+0)*40+cc], acc);
      acc = fmaf(uv.y, W_xp[(k4*4+1)*40+cc], acc);
      acc = fmaf(uv.z, W_xp[(k4*4+2)*40+cc], acc);
      acc = fmaf(uv.w, W_xp[(k4*4+3)*40+cc], acc);
    }
    xl[r][cc] = acc;
  }
  __syncthreads();
  float A[16], hsv[16];
  #pragma unroll
  for (int n=0;n<16;n++){ A[n] = -expf(A_log[d*16+n]); hsv[n]=0.f; }
  float wdt[DTR];
  #pragma unroll
  for (int j=0;j<DTR;j++) wdt[j] = Wdt[j*DI+d];
  float bdtv = bdt[d];
  float sdt = 0.f;
  for (int l=0;l<CLEN;++l) {
    float acc = bdtv;
    #pragma unroll
    for (int j=0;j<DTR;j++) acc = fmaf(xl[l][j], wdt[j], acc);
    float dtv = softplusf_(acc);
    sdt += dtv;
    float du = dtv * us[l][d];
    #pragma unroll
    for (int n=0;n<16;n++) {
      float a = expf(dtv*A[n]);
      hsv[n] = fmaf(a, hsv[n], du * xl[l][DTR+n]);
    }
  }
  int bd = (b<<8) + d;
  int base = (bd*CH + c)*16;
  #pragma unroll
  for (int n=0;n<16;n++) Hc[base+n] = hsv[n];
  Sdt[bd*CH + c] = sdt;
}

// pass 2: one thread per (b,d,n) chain; combine CH chunks; store chunk start states
__global__ void k_scan2(const float* __restrict__ A_log, const float* __restrict__ Hc,
                        const float* __restrict__ Sdt, float* __restrict__ Hst) {
  int idx = blockIdx.x*256 + threadIdx.x;   // 65536
  int n  = idx & 15;
  int bd = idx >> 4;
  int d  = bd & 255;
  float A = -expf(A_log[d*16+n]);
  float hs = 0.f;
  int base = bd*CH*16;
  #pragma unroll
  for (int c=0;c<CH;c++) {
    Hst[base + c*16 + n] = hs;
    float sdt = Sdt[bd*CH + c];
    hs = fmaf(expf(A*sdt), hs, Hc[base + c*16 + n]);
  }
}

// pass 3: replay chunk; y=(scan+u*D)*silu(z) into LDS; fused mo = ym@W_out.
__global__ void __launch_bounds__(256) k_scan3(
    const float* __restrict__ u, const float* __restrict__ z,
    const float* __restrict__ W_xp, const float* __restrict__ Wdt,
    const float* __restrict__ bdt, const float* __restrict__ A_log,
    const float* __restrict__ Dp, const float* __restrict__ Hst,
    const float* __restrict__ W_out, float* __restrict__ mo) {
  __shared__ float us[CLEN][256];
  __shared__ float ym[CLEN][256];
  __shared__ float xl[CLEN][40];
  int t = threadIdx.x;
  int b = blockIdx.x >> 5, c = blockIdx.x & 31, d = t;
  int l0 = c * CLEN;
  for (int i=t; i<CLEN*64; i+=256) {
    int r = i >> 6, q = i & 63;
    *(float4*)&us[r][q*4] = *(const float4*)&u[(((b<<9)+l0+r)<<8) + q*4];
  }
  __syncthreads();
  for (int i=t; i<CLEN*40; i+=256) {
    int r = i / 40, cc = i - r*40;
    float acc = 0.f;
    #pragma unroll 8
    for (int k4=0;k4<64;k4++) {
      float4 uv = *(const float4*)&us[r][k4*4];
      acc = fmaf(uv.x, W_xp[(k4*4+0)*40+cc], acc);
      acc = fmaf(uv.y, W_xp[(k4*4+1)*40+cc], acc);
      acc = fmaf(uv.z, W_xp[(k4*4+2)*40+cc], acc);
      acc = fmaf(uv.w, W_xp[(k4*4+3)*40+cc], acc);
    }
    xl[r][cc] = acc;
  }
  __syncthreads();
  int bd = (b<<8) + d;
  int base = (bd*CH + c)*16;
  float A[16], hsv[16];
  #pragma unroll
  for (int n=0;n<16;n++){ A[n] = -expf(A_log[d*16+n]); hsv[n] = Hst[base+n]; }
  float wdt[DTR];
  #pragma unroll
  for (int j=0;j<DTR;j++) wdt[j] = Wdt[j*DI+d];
  float bdtv = bdt[d];
  float Dv = Dp[d];
  for (int l=0;l<CLEN;++l) {
    int row = (b<<9) + l0 + l;
    float acc = bdtv;
    #pragma unroll
    for (int j=0;j<DTR;j++) acc = fmaf(xl[l][j], wdt[j], acc);
    float dtv = softplusf_(acc);
    float uv = us[l][d];
    float zv = z[(row<<8) + d];
    float du = dtv * uv;
    float y = 0.f;
    #pragma unroll
    for (int n=0;n<16;n++) {
      float a = expf(dtv*A[n]);
      hsv[n] = fmaf(a, hsv[n], du * xl[l][DTR+n]);
      y = fmaf(hsv[n], xl[l][DTR+DS+n], y);
    }
    y = fmaf(uv, Dv, y);
    ym[l][d] = y * (zv * sigmoidf_(zv));
  }
  __syncthreads();
  int cc = t & 127;
  int rg = (t >> 7) * 8;
  float acc[8] = {};
  for (int k4=0;k4<64;k4++) {
    float w0 = W_out[(k4*4+0)*DM+cc];
    float w1 = W_out[(k4*4+1)*DM+cc];
    float w2 = W_out[(k4*4+2)*DM+cc];
    float w3 = W_out[(k4*4+3)*DM+cc];
    #pragma unroll
    for (int o=0;o<8;o++) {
      float4 yv = *(const float4*)&ym[rg+o][k4*4];
      acc[o] = fmaf(yv.w, w3, fmaf(yv.z, w2, fmaf(yv.y, w1, fmaf(yv.x, w0, acc[o]))));
    }
  }
  #pragma unroll
  for (int o=0;o<8;o++) mo[((b<<9)+l0+rg+o)*DM + cc] = acc[o];
}

// final: pred partials = flat(16 x 65536) @ W_outproj(65536 x 3072), split-K.
// Each thread: 2 cols x all 16 rows. 6 n-tiles x 128 splits = 768 blocks (3/CU).
// W stream via nontemporal loads; k unrolled x4.
__global__ void __launch_bounds__(256) k_final(
    const float* __restrict__ flat, const float* __restrict__ W,
    float* __restrict__ part) {
  __shared__ float lds[KC][16];            // transposed: [kk][b], 32 KB
  int t = threadIdx.x;
  int n0 = blockIdx.x * 512;
  int k0 = blockIdx.y * KC;
  for (int i = t; i < 16*(KC/4); i += 256) {
    int bb  = i & 15;
    int kk4 = i >> 4;
    float4 v = *(const float4*)(flat + bb*KTOT + k0 + kk4*4);
    lds[kk4*4+0][bb] = v.x; lds[kk4*4+1][bb] = v.y;
    lds[kk4*4+2][bb] = v.z; lds[kk4*4+3][bb] = v.w;
  }
  __syncthreads();
  int c0 = n0 + t*2;
  float2 acc[16];
  #pragma unroll
  for (int b=0;b<16;b++) acc[b] = make_float2(0.f,0.f);
  const float* Wp = W + (size_t)k0*NCOL + c0;
  for (int kk=0; kk<KC; kk+=4) {
    f32x2 w0 = __builtin_nontemporal_load((const f32x2*)(Wp + (size_t)(kk+0)*NCOL));
    f32x2 w1 = __builtin_nontemporal_load((const f32x2*)(Wp + (size_t)(kk+1)*NCOL));
    f32x2 w2 = __builtin_nontemporal_load((const f32x2*)(Wp + (size_t)(kk+2)*NCOL));
    f32x2 w3 = __builtin_nontemporal_load((const f32x2*)(Wp + (size_t)(kk+3)*NCOL));
    const float4* f0 = (const float4*)&lds[kk+0][0];
    const float4* f1 = (const float4*)&lds[kk+1][0];
    const float4* f2 = (const float4*)&lds[kk+2][0];
    const float4* f3 = (const float4*)&lds[kk+3][0];
    #pragma unroll
    for (int q=0;q<4;q++) {
      float4 fa = f0[q], fb = f1[q], fc = f2[q], fd = f3[q];
      float fs0[4] = {fa.x,fa.y,fa.z,fa.w};
      float fs1[4] = {fb.x,fb.y,fb.z,fb.w};
      float fs2[4] = {fc.x,fc.y,fc.z,fc.w};
      float fs3[4] = {fd.x,fd.y,fd.z,fd.w};
      #pragma unroll
      for (int j=0;j<4;j++) {
        int b = q*4+j;
        acc[b].x=fmaf(fs0[j],w0.x,acc[b].x); acc[b].y=fmaf(fs0[j],w0.y,acc[b].y);
        acc[b].x=fmaf(fs1[j],w1.x,acc[b].x); acc[b].y=fmaf(fs1[j],w1.y,acc[b].y);
        acc[b].x=fmaf(fs2[j],w2.x,acc[b].x); acc[b].y=fmaf(fs2[j],w2.y,acc[b].y);
        acc[b].x=fmaf(fs3[j],w3.x,acc[b].x); acc[b].y=fmaf(fs3[j],w3.y,acc[b].y);
      }
    }
  }
  float* p = part + (size_t)blockIdx.y*OUTSZ;
  #pragma unroll
  for (int b=0;b<16;b++) {
    f32x2 v; v.x = acc[b].x; v.y = acc[b].y;
    __builtin_nontemporal_store(v, (f32x2*)(p + b*NCOL + c0));
  }
}

// out = sum_s part[s] + bias
__global__ void k_reduce(const float* __restrict__ part, const float* __restrict__ bias,
                         float* __restrict__ out) {
  int idx = blockIdx.x*256 + threadIdx.x; // OUTSZ
  float acc = bias[idx % NCOL];
  #pragma unroll 8
  for (int s=0;s<KS;s++)
    acc += __builtin_nontemporal_load(part + (size_t)s*OUTSZ + idx);
  out[idx] = acc;
}

extern "C" void kernel_launch(void* const* d_in, const int* in_sizes, int n_in,
                              void* d_out, int out_size, void* d_ws, size_t ws_size,
                              hipStream_t stream) {
  const float* x        = (const float*)d_in[0];
  const float* W_in     = (const float*)d_in[1];
  const float* b_in     = (const float*)d_in[2];
  const float* W_inproj = (const float*)d_in[3];
  const float* conv_w   = (const float*)d_in[4];
  const float* conv_b   = (const float*)d_in[5];
  const float* W_xproj  = (const float*)d_in[6];
  const float* W_dt     = (const float*)d_in[7];
  const float* b_dt     = (const float*)d_in[8];
  const float* A_log    = (const float*)d_in[9];
  const float* Dp       = (const float*)d_in[10];
  const float* W_out    = (const float*)d_in[11];
  const float* W_outproj= (const float*)d_in[12];
  const float* b_outproj= (const float*)d_in[13];
  float* out = (float*)d_out;
  float* ws  = (float*)d_ws;

  float* u    = ws;            // 2097152
  float* z    = ws + 2097152;  // 2097152
  float* Hc   = ws + 4194304;  // 2097152
  float* Sdt  = ws + 6291456;  // 131072
  float* Hst  = ws + 6422528;  // 2097152
  float* mo   = ws + 8519680;  // 1048576
  float* part = ws + 9568256;  // 6291456 -> total ~63 MB

  k_A     <<<1024, 256, 0, stream>>>(x, W_in, b_in, W_inproj, conv_w, conv_b, u, z);
  k_scan1 <<<512,  256, 0, stream>>>(u, W_xproj, W_dt, b_dt, A_log, Hc, Sdt);
  k_scan2 <<<256,  256, 0, stream>>>(A_log, Hc, Sdt, Hst);
  k_scan3 <<<512,  256, 0, stream>>>(u, z, W_xproj, W_dt, b_dt, A_log, Dp, Hst, W_out, mo);
  k_final <<<dim3(6, KS), 256, 0, stream>>>(mo, W_outproj, part);
  k_reduce<<<192,  256, 0, stream>>>(part, b_outproj, out);
}

// Round 10
// 289.843 us; speedup vs baseline: 1.3817x; 1.1686x over previous
//
#include <hip/hip_runtime.h>
#include <math.h>

#define NB 16
#define LL 512
#define CIN 32
#define DM 128
#define DS 16
#define DI 256
#define DTR 8
#define NCOL 3072
#define KTOT 65536
#define ROWS 8192
#define CH 64            // scan chunks
#define CLEN 8           // steps per chunk
#define KC 512           // k_final k-chunk
#define KS 128           // k_final splits
#define OUTSZ 49152

typedef float f32x2 __attribute__((ext_vector_type(2)));

__device__ __forceinline__ float sigmoidf_(float x){ return 1.f/(1.f+expf(-x)); }
__device__ __forceinline__ float softplusf_(float x){ return (x > 20.f) ? x : log1pf(expf(x)); }

// Fused front-end: h = x@W_in+b_in ; u_pre/z = h@W_inproj ; u = silu(conv4(u_pre)+cb).
// Block = 8 output rows; register-tiled GEMMs, each W_ip element read ONCE per block.
__global__ void __launch_bounds__(256) k_A(
    const float* __restrict__ x, const float* __restrict__ W_in,
    const float* __restrict__ b_in, const float* __restrict__ W_ip,
    const float* __restrict__ cw, const float* __restrict__ cb,
    float* __restrict__ u, float* __restrict__ z) {
  __shared__ float xs[11][32];
  __shared__ float hs[11][128];
  __shared__ float up[11][256];
  int t = threadIdx.x;
  int b  = blockIdx.x >> 6;
  int lt = blockIdx.x & 63;
  int l0 = lt * 8;
  // stage x rows l0-3 .. l0+7 (zero-fill for l<0)
  for (int i=t; i<11*32; i+=256) {
    int r = i >> 5, c = i & 31;
    int li = l0 - 3 + r;
    xs[r][c] = (li >= 0) ? x[((b<<9)+li)*CIN + c] : 0.f;
  }
  __syncthreads();
  // h = x@W_in + b_in (11 x 128)
  for (int i=t; i<11*128; i+=256) {
    int r = i >> 7, c = i & 127;
    float acc = b_in[c];
    #pragma unroll
    for (int k=0;k<CIN;k++) acc = fmaf(xs[r][k], W_in[k*DM+c], acc);
    hs[r][c] = acc;
  }
  __syncthreads();
  // u_pre (11 rows x 256 cols): thread = 4 cols x 3 rows (guard row 11)
  {
    int c0 = (t & 63)*4;
    int r0 = (t >> 6)*3;               // 0,3,6,9
    bool has2 = (r0+2 < 11);
    float acc[3][4] = {};
    for (int k=0;k<DM;k++) {
      float4 w = *(const float4*)(W_ip + k*512 + c0);
      float h0 = hs[r0][k], h1 = hs[r0+1][k];
      float h2 = has2 ? hs[r0+2][k] : 0.f;
      acc[0][0]=fmaf(h0,w.x,acc[0][0]); acc[0][1]=fmaf(h0,w.y,acc[0][1]);
      acc[0][2]=fmaf(h0,w.z,acc[0][2]); acc[0][3]=fmaf(h0,w.w,acc[0][3]);
      acc[1][0]=fmaf(h1,w.x,acc[1][0]); acc[1][1]=fmaf(h1,w.y,acc[1][1]);
      acc[1][2]=fmaf(h1,w.z,acc[1][2]); acc[1][3]=fmaf(h1,w.w,acc[1][3]);
      acc[2][0]=fmaf(h2,w.x,acc[2][0]); acc[2][1]=fmaf(h2,w.y,acc[2][1]);
      acc[2][2]=fmaf(h2,w.z,acc[2][2]); acc[2][3]=fmaf(h2,w.w,acc[2][3]);
    }
    *(float4*)&up[r0  ][c0] = make_float4(acc[0][0],acc[0][1],acc[0][2],acc[0][3]);
    *(float4*)&up[r0+1][c0] = make_float4(acc[1][0],acc[1][1],acc[1][2],acc[1][3]);
    if (has2)
      *(float4*)&up[r0+2][c0] = make_float4(acc[2][0],acc[2][1],acc[2][2],acc[2][3]);
  }
  // z (8 rows x 256 cols): thread = 4 cols x 2 rows; z row rz uses hs[3+rz]
  {
    int c0 = (t & 63)*4;
    int r0 = (t >> 6)*2;               // 0,2,4,6
    float acc[2][4] = {};
    for (int k=0;k<DM;k++) {
      float4 w = *(const float4*)(W_ip + k*512 + 256 + c0);
      float h0 = hs[3+r0][k], h1 = hs[3+r0+1][k];
      acc[0][0]=fmaf(h0,w.x,acc[0][0]); acc[0][1]=fmaf(h0,w.y,acc[0][1]);
      acc[0][2]=fmaf(h0,w.z,acc[0][2]); acc[0][3]=fmaf(h0,w.w,acc[0][3]);
      acc[1][0]=fmaf(h1,w.x,acc[1][0]); acc[1][1]=fmaf(h1,w.y,acc[1][1]);
      acc[1][2]=fmaf(h1,w.z,acc[1][2]); acc[1][3]=fmaf(h1,w.w,acc[1][3]);
    }
    #pragma unroll
    for (int i=0;i<2;i++) {
      int gr = (b<<9) + l0 + r0 + i;
      *(float4*)(z + gr*DI + c0) =
        make_float4(acc[i][0],acc[i][1],acc[i][2],acc[i][3]);
    }
  }
  __syncthreads();
  // conv + silu: 8 x 256
  for (int i=t; i<8*256; i+=256) {
    int r = i >> 8, d = i & 255;
    float s = cb[d];
    #pragma unroll
    for (int j=0;j<4;j++) {
      int li = l0 + r - 3 + j;
      if (li >= 0) s = fmaf(cw[d*4+j], up[r+j][d], s);
    }
    int gr = (b<<9) + l0 + r;
    u[gr*DI + d] = s * sigmoidf_(s);
  }
}

// scan pass 1: block=(b,chunk), thread=d. xproj (dt+B) + dt inline from LDS u.
__global__ void __launch_bounds__(256) k_scan1(
    const float* __restrict__ u, const float* __restrict__ W_xp,
    const float* __restrict__ Wdt, const float* __restrict__ bdt,
    const float* __restrict__ A_log,
    float* __restrict__ Hc, float* __restrict__ Sdt) {
  __shared__ float us[CLEN][256];
  __shared__ float xl[CLEN][24];
  int t = threadIdx.x;
  int b = blockIdx.x >> 6, c = blockIdx.x & 63, d = t;
  int l0 = c * CLEN;
  for (int i=t; i<CLEN*64; i+=256) {
    int r = i >> 6, q = i & 63;
    *(float4*)&us[r][q*4] = *(const float4*)&u[(((b<<9)+l0+r)<<8) + q*4];
  }
  __syncthreads();
  for (int i=t; i<CLEN*24; i+=256) {
    int r = i / 24, cc = i - r*24;
    float acc = 0.f;
    #pragma unroll 8
    for (int k4=0;k4<64;k4++) {
      float4 uv = *(const float4*)&us[r][k4*4];
      acc = fmaf(uv.x, W_xp[(k4*4+0)*40+cc], acc);
      acc = fmaf(uv.y, W_xp[(k4*4+1)*40+cc], acc);
      acc = fmaf(uv.z, W_xp[(k4*4+2)*40+cc], acc);
      acc = fmaf(uv.w, W_xp[(k4*4+3)*40+cc], acc);
    }
    xl[r][cc] = acc;
  }
  __syncthreads();
  float A[16], hsv[16];
  #pragma unroll
  for (int n=0;n<16;n++){ A[n] = -expf(A_log[d*16+n]); hsv[n]=0.f; }
  float wdt[DTR];
  #pragma unroll
  for (int j=0;j<DTR;j++) wdt[j] = Wdt[j*DI+d];
  float bdtv = bdt[d];
  float sdt = 0.f;
  for (int l=0;l<CLEN;++l) {
    float acc = bdtv;
    #pragma unroll
    for (int j=0;j<DTR;j++) acc = fmaf(xl[l][j], wdt[j], acc);
    float dtv = softplusf_(acc);
    sdt += dtv;
    float du = dtv * us[l][d];
    #pragma unroll
    for (int n=0;n<16;n++) {
      float a = expf(dtv*A[n]);
      hsv[n] = fmaf(a, hsv[n], du * xl[l][DTR+n]);
    }
  }
  int bd = (b<<8) + d;
  int base = (bd*CH + c)*16;
  #pragma unroll
  for (int n=0;n<16;n++) Hc[base+n] = hsv[n];
  Sdt[bd*CH + c] = sdt;
}

// pass 2: one thread per (b,d,n) chain; combine CH chunks; store chunk start states
__global__ void k_scan2(const float* __restrict__ A_log, const float* __restrict__ Hc,
                        const float* __restrict__ Sdt, float* __restrict__ Hst) {
  int idx = blockIdx.x*256 + threadIdx.x;   // 65536
  int n  = idx & 15;
  int bd = idx >> 4;
  int d  = bd & 255;
  float A = -expf(A_log[d*16+n]);
  float hs = 0.f;
  int base = bd*CH*16;
  for (int c=0;c<CH;c++) {
    Hst[base + c*16 + n] = hs;
    float sdt = Sdt[bd*CH + c];
    hs = fmaf(expf(A*sdt), hs, Hc[base + c*16 + n]);
  }
}

// pass 3: replay chunk; y=(scan+u*D)*silu(z) into LDS; fused mo = ym@W_out.
__global__ void __launch_bounds__(256) k_scan3(
    const float* __restrict__ u, const float* __restrict__ z,
    const float* __restrict__ W_xp, const float* __restrict__ Wdt,
    const float* __restrict__ bdt, const float* __restrict__ A_log,
    const float* __restrict__ Dp, const float* __restrict__ Hst,
    const float* __restrict__ W_out, float* __restrict__ mo) {
  __shared__ float us[CLEN][256];
  __shared__ float ym[CLEN][256];
  __shared__ float xl[CLEN][40];
  int t = threadIdx.x;
  int b = blockIdx.x >> 6, c = blockIdx.x & 63, d = t;
  int l0 = c * CLEN;
  for (int i=t; i<CLEN*64; i+=256) {
    int r = i >> 6, q = i & 63;
    *(float4*)&us[r][q*4] = *(const float4*)&u[(((b<<9)+l0+r)<<8) + q*4];
  }
  __syncthreads();
  for (int i=t; i<CLEN*40; i+=256) {
    int r = i / 40, cc = i - r*40;
    float acc = 0.f;
    #pragma unroll 8
    for (int k4=0;k4<64;k4++) {
      float4 uv = *(const float4*)&us[r][k4*4];
      acc = fmaf(uv.x, W_xp[(k4*4+0)*40+cc], acc);
      acc = fmaf(uv.y, W_xp[(k4*4+1)*40+cc], acc);
      acc = fmaf(uv.z, W_xp[(k4*4+2)*40+cc], acc);
      acc = fmaf(uv.w, W_xp[(k4*4+3)*40+cc], acc);
    }
    xl[r][cc] = acc;
  }
  __syncthreads();
  int bd = (b<<8) + d;
  int base = (bd*CH + c)*16;
  float A[16], hsv[16];
  #pragma unroll
  for (int n=0;n<16;n++){ A[n] = -expf(A_log[d*16+n]); hsv[n] = Hst[base+n]; }
  float wdt[DTR];
  #pragma unroll
  for (int j=0;j<DTR;j++) wdt[j] = Wdt[j*DI+d];
  float bdtv = bdt[d];
  float Dv = Dp[d];
  for (int l=0;l<CLEN;++l) {
    int row = (b<<9) + l0 + l;
    float acc = bdtv;
    #pragma unroll
    for (int j=0;j<DTR;j++) acc = fmaf(xl[l][j], wdt[j], acc);
    float dtv = softplusf_(acc);
    float uv = us[l][d];
    float zv = z[(row<<8) + d];
    float du = dtv * uv;
    float y = 0.f;
    #pragma unroll
    for (int n=0;n<16;n++) {
      float a = expf(dtv*A[n]);
      hsv[n] = fmaf(a, hsv[n], du * xl[l][DTR+n]);
      y = fmaf(hsv[n], xl[l][DTR+DS+n], y);
    }
    y = fmaf(uv, Dv, y);
    ym[l][d] = y * (zv * sigmoidf_(zv));
  }
  __syncthreads();
  // mo = ym @ W_out for the 8 rows: thread = (col cc, 4-row group)
  int cc = t & 127;
  int rg = (t >> 7) * 4;
  float acc[4] = {};
  for (int k4=0;k4<64;k4++) {
    float w0 = W_out[(k4*4+0)*DM+cc];
    float w1 = W_out[(k4*4+1)*DM+cc];
    float w2 = W_out[(k4*4+2)*DM+cc];
    float w3 = W_out[(k4*4+3)*DM+cc];
    #pragma unroll
    for (int o=0;o<4;o++) {
      float4 yv = *(const float4*)&ym[rg+o][k4*4];
      acc[o] = fmaf(yv.w, w3, fmaf(yv.z, w2, fmaf(yv.y, w1, fmaf(yv.x, w0, acc[o]))));
    }
  }
  #pragma unroll
  for (int o=0;o<4;o++) mo[((b<<9)+l0+rg+o)*DM + cc] = acc[o];
}

// final: pred partials = flat(16 x 65536) @ W_outproj(65536 x 3072), split-K.
// Each thread: 2 cols x all 16 rows. 6 n-tiles x 128 splits = 768 blocks (3/CU).
// W stream via nontemporal loads; k unrolled x4. (unchanged from R9)
__global__ void __launch_bounds__(256) k_final(
    const float* __restrict__ flat, const float* __restrict__ W,
    float* __restrict__ part) {
  __shared__ float lds[KC][16];            // transposed: [kk][b], 32 KB
  int t = threadIdx.x;
  int n0 = blockIdx.x * 512;
  int k0 = blockIdx.y * KC;
  for (int i = t; i < 16*(KC/4); i += 256) {
    int bb  = i & 15;
    int kk4 = i >> 4;
    float4 v = *(const float4*)(flat + bb*KTOT + k0 + kk4*4);
    lds[kk4*4+0][bb] = v.x; lds[kk4*4+1][bb] = v.y;
    lds[kk4*4+2][bb] = v.z; lds[kk4*4+3][bb] = v.w;
  }
  __syncthreads();
  int c0 = n0 + t*2;
  float2 acc[16];
  #pragma unroll
  for (int b=0;b<16;b++) acc[b] = make_float2(0.f,0.f);
  const float* Wp = W + (size_t)k0*NCOL + c0;
  for (int kk=0; kk<KC; kk+=4) {
    f32x2 w0 = __builtin_nontemporal_load((const f32x2*)(Wp + (size_t)(kk+0)*NCOL));
    f32x2 w1 = __builtin_nontemporal_load((const f32x2*)(Wp + (size_t)(kk+1)*NCOL));
    f32x2 w2 = __builtin_nontemporal_load((const f32x2*)(Wp + (size_t)(kk+2)*NCOL));
    f32x2 w3 = __builtin_nontemporal_load((const f32x2*)(Wp + (size_t)(kk+3)*NCOL));
    const float4* f0 = (const float4*)&lds[kk+0][0];
    const float4* f1 = (const float4*)&lds[kk+1][0];
    const float4* f2 = (const float4*)&lds[kk+2][0];
    const float4* f3 = (const float4*)&lds[kk+3][0];
    #pragma unroll
    for (int q=0;q<4;q++) {
      float4 fa = f0[q], fb = f1[q], fc = f2[q], fd = f3[q];
      float fs0[4] = {fa.x,fa.y,fa.z,fa.w};
      float fs1[4] = {fb.x,fb.y,fb.z,fb.w};
      float fs2[4] = {fc.x,fc.y,fc.z,fc.w};
      float fs3[4] = {fd.x,fd.y,fd.z,fd.w};
      #pragma unroll
      for (int j=0;j<4;j++) {
        int b = q*4+j;
        acc[b].x=fmaf(fs0[j],w0.x,acc[b].x); acc[b].y=fmaf(fs0[j],w0.y,acc[b].y);
        acc[b].x=fmaf(fs1[j],w1.x,acc[b].x); acc[b].y=fmaf(fs1[j],w1.y,acc[b].y);
        acc[b].x=fmaf(fs2[j],w2.x,acc[b].x); acc[b].y=fmaf(fs2[j],w2.y,acc[b].y);
        acc[b].x=fmaf(fs3[j],w3.x,acc[b].x); acc[b].y=fmaf(fs3[j],w3.y,acc[b].y);
      }
    }
  }
  float* p = part + (size_t)blockIdx.y*OUTSZ;
  #pragma unroll
  for (int b=0;b<16;b++) {
    f32x2 v; v.x = acc[b].x; v.y = acc[b].y;
    __builtin_nontemporal_store(v, (f32x2*)(p + b*NCOL + c0));
  }
}

// out = sum_s part[s] + bias
__global__ void k_reduce(const float* __restrict__ part, const float* __restrict__ bias,
                         float* __restrict__ out) {
  int idx = blockIdx.x*256 + threadIdx.x; // OUTSZ
  float acc = bias[idx % NCOL];
  #pragma unroll 8
  for (int s=0;s<KS;s++)
    acc += __builtin_nontemporal_load(part + (size_t)s*OUTSZ + idx);
  out[idx] = acc;
}

extern "C" void kernel_launch(void* const* d_in, const int* in_sizes, int n_in,
                              void* d_out, int out_size, void* d_ws, size_t ws_size,
                              hipStream_t stream) {
  const float* x        = (const float*)d_in[0];
  const float* W_in     = (const float*)d_in[1];
  const float* b_in     = (const float*)d_in[2];
  const float* W_inproj = (const float*)d_in[3];
  const float* conv_w   = (const float*)d_in[4];
  const float* conv_b   = (const float*)d_in[5];
  const float* W_xproj  = (const float*)d_in[6];
  const float* W_dt     = (const float*)d_in[7];
  const float* b_dt     = (const float*)d_in[8];
  const float* A_log    = (const float*)d_in[9];
  const float* Dp       = (const float*)d_in[10];
  const float* W_out    = (const float*)d_in[11];
  const float* W_outproj= (const float*)d_in[12];
  const float* b_outproj= (const float*)d_in[13];
  float* out = (float*)d_out;
  float* ws  = (float*)d_ws;

  float* u    = ws;             // 2097152
  float* z    = ws + 2097152;   // 2097152
  float* Hc   = ws + 4194304;   // 4194304 (NB*DI*CH*16)
  float* Sdt  = ws + 8388608;   // 262144
  float* Hst  = ws + 8650752;   // 4194304
  float* mo   = ws + 12845056;  // 1048576
  float* part = ws + 13893632;  // 6291456 -> total ~80.7 MB

  k_A     <<<1024, 256, 0, stream>>>(x, W_in, b_in, W_inproj, conv_w, conv_b, u, z);
  k_scan1 <<<1024, 256, 0, stream>>>(u, W_xproj, W_dt, b_dt, A_log, Hc, Sdt);
  k_scan2 <<<256,  256, 0, stream>>>(A_log, Hc, Sdt, Hst);
  k_scan3 <<<1024, 256, 0, stream>>>(u, z, W_xproj, W_dt, b_dt, A_log, Dp, Hst, W_out, mo);
  k_final <<<dim3(6, KS), 256, 0, stream>>>(mo, W_outproj, part);
  k_reduce<<<192,  256, 0, stream>>>(part, b_outproj, out);
}